// Round 3
// baseline (186.001 us; speedup 1.0000x reference)
//
#include <hip/hip_runtime.h>
#include <hip/hip_bf16.h>

#define IMG 1024
#define OUTW 1018
#define RS 16                  // output rows owned per strip
#define NSTRIP 64              // 64*16 = 1024: strips tile rows exactly
#define NXW 4                  // waves across width: 4*256 = 1024 cols
#define NBATCH 16
#define NWAVE (NBATCH * NSTRIP * NXW)  // 4096 working waves
#define NBLK (NWAVE / 4)               // 1024 blocks = exactly 4 blocks/CU
#define NSTEP (RS + 8)                 // 24 row-steps per strip
#define NTC ((NSTEP + 8) / 9)          // 3 outer ring cycles
#define EPSF 2.2204460492503131e-16f
#define INV81 (1.0f / 81.0f)

// Linear horizontal 9-sum window update (bf16 ring for exact cancel).
__device__ __forceinline__ void hsum_update(const float* __restrict__ arr,
                                            float* __restrict__ wX,
                                            __hip_bfloat162* __restrict__ g) {
  float h0 = arr[0] + arr[1] + arr[2] + arr[3] + arr[4] + arr[5] + arr[6] +
             arr[7] + arr[8];
  float h1 = h0 - arr[0] + arr[9];
  float h2 = h1 - arr[1] + arr[10];
  float h3 = h2 - arr[2] + arr[11];
  __hip_bfloat162 plo = __float22bfloat162_rn(make_float2(h0, h1));
  __hip_bfloat162 phi = __float22bfloat162_rn(make_float2(h2, h3));
  float2 nlo = __bfloat1622float2(plo), nhi = __bfloat1622float2(phi);
  float2 olo = __bfloat1622float2(g[0]), ohi = __bfloat1622float2(g[1]);
  wX[0] += nlo.x - olo.x;
  wX[1] += nlo.y - olo.y;
  wX[2] += nhi.x - ohi.x;
  wX[3] += nhi.y - ohi.y;
  g[0] = plo;
  g[1] = phi;
}

// Quadratic (a[p]*b[p]) horizontal 9-sum window update, fmaf-fused.
__device__ __forceinline__ void hsum_update_sq(const float* __restrict__ a,
                                               const float* __restrict__ b,
                                               float* __restrict__ wX,
                                               __hip_bfloat162* __restrict__ g) {
  float h0 = a[0] * b[0];
  h0 = fmaf(a[1], b[1], h0); h0 = fmaf(a[2], b[2], h0);
  h0 = fmaf(a[3], b[3], h0); h0 = fmaf(a[4], b[4], h0);
  h0 = fmaf(a[5], b[5], h0); h0 = fmaf(a[6], b[6], h0);
  h0 = fmaf(a[7], b[7], h0); h0 = fmaf(a[8], b[8], h0);
  float h1 = fmaf(a[9],  b[9],  fmaf(-a[0], b[0], h0));
  float h2 = fmaf(a[10], b[10], fmaf(-a[1], b[1], h1));
  float h3 = fmaf(a[11], b[11], fmaf(-a[2], b[2], h2));
  __hip_bfloat162 plo = __float22bfloat162_rn(make_float2(h0, h1));
  __hip_bfloat162 phi = __float22bfloat162_rn(make_float2(h2, h3));
  float2 nlo = __bfloat1622float2(plo), nhi = __bfloat1622float2(phi);
  float2 olo = __bfloat1622float2(g[0]), ohi = __bfloat1622float2(g[1]);
  wX[0] += nlo.x - olo.x;
  wX[1] += nlo.y - olo.y;
  wX[2] += nhi.x - ohi.x;
  wX[3] += nhi.y - ohi.y;
  g[0] = plo;
  g[1] = phi;
}

// launch_bounds(256,1): (256,4) forces a 64-VGPR target -> 315 MB scratch
// spill (round 1). Natural allocation 128 VGPR = 4 waves/SIMD resident.
__global__ __launch_bounds__(256, 1) void fused_kernel(
    const float* __restrict__ I, const float* __restrict__ J,
    double2* __restrict__ partial) {
  const int lane = threadIdx.x & 63;
  const int wid = blockIdx.x * 4 + (threadIdx.x >> 6);
  float acc_cc = 0.f, acc_sm = 0.f;
  {
    const int b = wid / (NSTRIP * NXW);
    const int rem = wid - b * (NSTRIP * NXW);
    const int strip = rem / NXW;
    const int xw = rem - strip * NXW;
    const int R0 = strip * RS;
    const int c0 = xw * 256 + 4 * lane;      // first owned column
    const int ccL = max(c0 - 1, 0);          // left-halo scalar col (clamped)
    const int cc2 = min(c0 + 4, IMG - 4);    // patch-load cols (lanes 62-63)
    const int cc3 = min(c0 + 8, IMG - 4);
    const bool vL = (c0 > 0);
    const bool v2 = (c0 + 4 <= IMG - 4);
    const bool v3 = (c0 + 8 <= IMG - 4);
    const bool e1 = (lane >= 63);            // shfl_down(.,1) out of wave
    const bool e2 = (lane >= 62);            // shfl_down(.,2) out of wave
    const float* Ib = I + (size_t)b * (IMG * IMG);
    const float* Jb = J + (size_t)b * (IMG * IMG);

    // bf16-packed ring: 9 rows x 5 quantities x 4 cols = 90 VGPRs
    __hip_bfloat162 gI[9][2], gJ[9][2], gII[9][2], gJJ[9][2], gIJ[9][2];
    const __hip_bfloat162 z2 = __float22bfloat162_rn(make_float2(0.f, 0.f));
#pragma unroll
    for (int k = 0; k < 9; ++k) {
      gI[k][0] = z2; gI[k][1] = z2; gJ[k][0] = z2; gJ[k][1] = z2;
      gII[k][0] = z2; gII[k][1] = z2; gJJ[k][0] = z2; gJJ[k][1] = z2;
      gIJ[k][0] = z2; gIJ[k][1] = z2;
    }
    float wI[4] = {0,0,0,0}, wJ[4] = {0,0,0,0}, wII[4] = {0,0,0,0},
          wJJ[4] = {0,0,0,0}, wIJ[4] = {0,0,0,0};
    float prevI[4] = {0,0,0,0};

    for (int tc = 0; tc < NTC; ++tc) {
#pragma unroll
      for (int u = 0; u < 9; ++u) {
        const int t = tc * 9 + u;
        if (t < NSTEP) {
          const int r = R0 - 1 + t;      // input row
          float iw[12], jw[12];
          if (r >= 0 && r < IMG) {       // wave-uniform
            const float* rpI = Ib + ((size_t)r << 10);
            const float* rpJ = Jb + ((size_t)r << 10);
            // Per image: 1 scalar (left halo) + 1 float4 (owned cols).
            // Right halo comes from neighbor lanes via shfl; only lanes
            // 62-63 (wave edge) patch with exec-masked loads (~2/64 lanes).
            float lI = rpI[ccL], lJ = rpJ[ccL];
            float4 A1 = *(const float4*)(rpI + c0);
            float4 B1 = *(const float4*)(rpJ + c0);
            float4 A2 = make_float4(0,0,0,0), A3 = make_float4(0,0,0,0);
            float4 B2 = make_float4(0,0,0,0), B3 = make_float4(0,0,0,0);
            if (lane >= 62) {            // divergent, 2 lanes: halo patch
              A2 = *(const float4*)(rpI + cc2);
              A3 = *(const float4*)(rpI + cc3);
              B2 = *(const float4*)(rpJ + cc2);
              B3 = *(const float4*)(rpJ + cc3);
            }
            float i5 = __shfl_down(A1.x, 1), i6 = __shfl_down(A1.y, 1);
            float i7 = __shfl_down(A1.z, 1), i8 = __shfl_down(A1.w, 1);
            float i9 = __shfl_down(A1.x, 2), i10 = __shfl_down(A1.y, 2);
            float i11 = __shfl_down(A1.z, 2);
            float j5 = __shfl_down(B1.x, 1), j6 = __shfl_down(B1.y, 1);
            float j7 = __shfl_down(B1.z, 1), j8 = __shfl_down(B1.w, 1);
            float j9 = __shfl_down(B1.x, 2), j10 = __shfl_down(B1.y, 2);
            float j11 = __shfl_down(B1.z, 2);
            iw[0] = vL ? lI : 0.f;             jw[0] = vL ? lJ : 0.f;
            iw[1] = A1.x; iw[2] = A1.y; iw[3] = A1.z; iw[4] = A1.w;
            jw[1] = B1.x; jw[2] = B1.y; jw[3] = B1.z; jw[4] = B1.w;
            iw[5] = v2 ? (e1 ? A2.x : i5) : 0.f;
            iw[6] = v2 ? (e1 ? A2.y : i6) : 0.f;
            iw[7] = v2 ? (e1 ? A2.z : i7) : 0.f;
            iw[8] = v2 ? (e1 ? A2.w : i8) : 0.f;
            jw[5] = v2 ? (e1 ? B2.x : j5) : 0.f;
            jw[6] = v2 ? (e1 ? B2.y : j6) : 0.f;
            jw[7] = v2 ? (e1 ? B2.z : j7) : 0.f;
            jw[8] = v2 ? (e1 ? B2.w : j8) : 0.f;
            iw[9]  = v3 ? (e2 ? A3.x : i9)  : 0.f;
            iw[10] = v3 ? (e2 ? A3.y : i10) : 0.f;
            iw[11] = v3 ? (e2 ? A3.z : i11) : 0.f;
            jw[9]  = v3 ? (e2 ? B3.x : j9)  : 0.f;
            jw[10] = v3 ? (e2 ? B3.y : j10) : 0.f;
            jw[11] = v3 ? (e2 ? B3.z : j11) : 0.f;
          } else {
#pragma unroll
            for (int p = 0; p < 12; ++p) { iw[p] = 0.f; jw[p] = 0.f; }
          }

          hsum_update(iw, wI, gI[u]);
          hsum_update(jw, wJ, gJ[u]);
          hsum_update_sq(iw, iw, wII, gII[u]);
          hsum_update_sq(jw, jw, wJJ, gJJ[u]);
          hsum_update_sq(iw, jw, wIJ, gIJ[u]);

          // smoothness dy: pairs (r-1, r) with r-1 owned by this strip
          if (r >= R0 + 1 && r <= R0 + RS && r <= IMG - 1) {   // uniform
#pragma unroll
            for (int q = 0; q < 4; ++q) {
              float d = iw[1 + q] - prevI[q];
              acc_sm = fmaf(d, d, acc_sm);
            }
          }
          // smoothness dx at owned rows
          if (r >= R0 && r <= R0 + RS - 1 && r <= IMG - 1) {   // uniform
#pragma unroll
            for (int q = 0; q < 4; ++q) {
              float d = iw[2 + q] - iw[1 + q];
              d = (c0 + q < IMG - 1) ? d : 0.f;
              acc_sm = fmaf(d, d, acc_sm);
            }
          }
          prevI[0] = iw[1]; prevI[1] = iw[2]; prevI[2] = iw[3]; prevI[3] = iw[4];

          // emit output row oy = R0 + t - 8 once window complete
          if (t >= 8) {                                        // uniform
            const int oy = R0 + t - 8;
            if (oy < OUTW) {                                   // uniform
#pragma unroll
              for (int q = 0; q < 4; ++q) {
                if (c0 + q < OUTW) {
                  float cross = fmaf(-(wI[q] * wJ[q]), INV81, wIJ[q]);
                  float iva   = fmaf(-(wI[q] * wI[q]), INV81, wII[q]);
                  float jva   = fmaf(-(wJ[q] * wJ[q]), INV81, wJJ[q]);
                  float den   = fmaf(iva, jva, EPSF);
                  acc_cc += cross * cross * __builtin_amdgcn_rcpf(den);
                }
              }
            }
          }
        }
      }
    }
  }

  // per-wave shuffle reduce, then per-block LDS reduce; one double2 per block
  float vc = acc_cc, vs = acc_sm;
#pragma unroll
  for (int off = 32; off > 0; off >>= 1) {
    vc += __shfl_down(vc, off);
    vs += __shfl_down(vs, off);
  }
  __shared__ double2 red[4];
  if (lane == 0) red[threadIdx.x >> 6] = make_double2((double)vc, (double)vs);
  __syncthreads();
  if (threadIdx.x == 0) {
    partial[blockIdx.x] = make_double2(red[0].x + red[1].x + red[2].x + red[3].x,
                                       red[0].y + red[1].y + red[2].y + red[3].y);
  }
}

__global__ __launch_bounds__(256) void fin_kernel(const double2* __restrict__ partial,
                                                  float* __restrict__ out) {
  double s_cc = 0.0, s_sm = 0.0;
  for (int i = threadIdx.x; i < NBLK; i += 256) {
    double2 p = partial[i];
    s_cc += p.x; s_sm += p.y;
  }
#pragma unroll
  for (int off = 32; off > 0; off >>= 1) {
    s_cc += __shfl_down(s_cc, off);
    s_sm += __shfl_down(s_sm, off);
  }
  __shared__ double r1[4], r2[4];
  if ((threadIdx.x & 63) == 0) { r1[threadIdx.x >> 6] = s_cc; r2[threadIdx.x >> 6] = s_sm; }
  __syncthreads();
  if (threadIdx.x == 0) {
    const double cc = (r1[0] + r1[1] + r1[2] + r1[3]) /
                      (double)((size_t)NBATCH * OUTW * OUTW);
    const double sm = (r2[0] + r2[1] + r2[2] + r2[3]) /
                      (2.0 * (double)((size_t)NBATCH * IMG * (IMG - 1)));
    out[0] = (float)(-cc + 0.1 * sm);
  }
}

extern "C" void kernel_launch(void* const* d_in, const int* in_sizes, int n_in,
                              void* d_out, int out_size, void* d_ws, size_t ws_size,
                              hipStream_t stream) {
  const float* y  = (const float*)d_in[0];
  const float* yt = (const float*)d_in[1];
  float* out = (float*)d_out;
  double2* partial = (double2*)d_ws;
  fused_kernel<<<NBLK, 256, 0, stream>>>(y, yt, partial);
  fin_kernel<<<1, 256, 0, stream>>>(partial, out);
}

// Round 5
// 173.072 us; speedup vs baseline: 1.0747x; 1.0747x over previous
//
#include <hip/hip_runtime.h>
#include <hip/hip_bf16.h>

#define IMG 1024
#define OUTW 1018
#define RS 32                  // output rows owned per strip
#define NSTRIP 32              // 32*32 = 1024: strips tile rows exactly
#define NXW 4                  // waves across width: 4*256 = 1024 cols
#define NBATCH 16
#define NWAVE (NBATCH * NSTRIP * NXW)  // 2048 working waves
#define NBLK (NWAVE / 4)               // 512 blocks = exactly 2 blocks/CU, balanced
#define NSTEP (RS + 8)                 // 40 row-steps per strip
#define NTC ((NSTEP + 8) / 9)          // 5 outer ring cycles (45 slots, 5 skipped)
#define EPSF 2.2204460492503131e-16f
#define INV81 (1.0f / 81.0f)

// Linear horizontal 9-sum window update (bf16 ring for exact cancel).
__device__ __forceinline__ void hsum_update(const float* __restrict__ arr,
                                            float* __restrict__ wX,
                                            __hip_bfloat162* __restrict__ g) {
  float h0 = arr[0] + arr[1] + arr[2] + arr[3] + arr[4] + arr[5] + arr[6] +
             arr[7] + arr[8];
  float h1 = h0 - arr[0] + arr[9];
  float h2 = h1 - arr[1] + arr[10];
  float h3 = h2 - arr[2] + arr[11];
  __hip_bfloat162 plo = __float22bfloat162_rn(make_float2(h0, h1));
  __hip_bfloat162 phi = __float22bfloat162_rn(make_float2(h2, h3));
  float2 nlo = __bfloat1622float2(plo), nhi = __bfloat1622float2(phi);
  float2 olo = __bfloat1622float2(g[0]), ohi = __bfloat1622float2(g[1]);
  wX[0] += nlo.x - olo.x;
  wX[1] += nlo.y - olo.y;
  wX[2] += nhi.x - ohi.x;
  wX[3] += nhi.y - ohi.y;
  g[0] = plo;
  g[1] = phi;
}

// Quadratic (a[p]*b[p]) horizontal 9-sum window update, fmaf-fused.
__device__ __forceinline__ void hsum_update_sq(const float* __restrict__ a,
                                               const float* __restrict__ b,
                                               float* __restrict__ wX,
                                               __hip_bfloat162* __restrict__ g) {
  float h0 = a[0] * b[0];
  h0 = fmaf(a[1], b[1], h0); h0 = fmaf(a[2], b[2], h0);
  h0 = fmaf(a[3], b[3], h0); h0 = fmaf(a[4], b[4], h0);
  h0 = fmaf(a[5], b[5], h0); h0 = fmaf(a[6], b[6], h0);
  h0 = fmaf(a[7], b[7], h0); h0 = fmaf(a[8], b[8], h0);
  float h1 = fmaf(a[9],  b[9],  fmaf(-a[0], b[0], h0));
  float h2 = fmaf(a[10], b[10], fmaf(-a[1], b[1], h1));
  float h3 = fmaf(a[11], b[11], fmaf(-a[2], b[2], h2));
  __hip_bfloat162 plo = __float22bfloat162_rn(make_float2(h0, h1));
  __hip_bfloat162 phi = __float22bfloat162_rn(make_float2(h2, h3));
  float2 nlo = __bfloat1622float2(plo), nhi = __bfloat1622float2(phi);
  float2 olo = __bfloat1622float2(g[0]), ohi = __bfloat1622float2(g[1]);
  wX[0] += nlo.x - olo.x;
  wX[1] += nlo.y - olo.y;
  wX[2] += nhi.x - ohi.x;
  wX[3] += nhi.y - ohi.y;
  g[0] = plo;
  g[1] = phi;
}

// launch_bounds(256,1): (256,4) forces a 64-VGPR target -> 315 MB scratch
// spill (round 1). Natural allocation 128 VGPR.
__global__ __launch_bounds__(256, 1) void fused_kernel(
    const float* __restrict__ I, const float* __restrict__ J,
    double2* __restrict__ partial) {
  const int lane = threadIdx.x & 63;
  const int wid = blockIdx.x * 4 + (threadIdx.x >> 6);
  float acc_cc = 0.f, acc_sm = 0.f;
  {
    const int b = wid / (NSTRIP * NXW);
    const int rem = wid - b * (NSTRIP * NXW);
    const int strip = rem / NXW;
    const int xw = rem - strip * NXW;
    const int R0 = strip * RS;
    const int base = xw * 256;               // wave's first column
    const int c0 = base + 4 * lane;          // lane's first owned column
    // Edge-patch lanes: lane 0 loads cols base-4..base-1 (left halo .w),
    // lane 62 loads base+256..259, lane 63 loads base+260..263 (right halo).
    // On image borders (xw==0 left, xw==3 right) the patch is NOT loaded:
    // pre-zeroed P registers then implement the conv zero-pad for free,
    // which also removes all vL/v2/v3 cndmasks from the hot loop.
    int cp = c0;
    if (lane == 0)  cp = base - 4;
    if (lane == 62) cp = base + 256;
    if (lane == 63) cp = base + 260;
    cp = min(max(cp, 0), IMG - 4);           // safe addr even on masked-off lanes
    const bool do_patch = (lane == 0 && xw > 0) || (lane >= 62 && xw < 3);
    const bool isL  = (lane == 0);
    const bool isE1 = (lane == 63);
    const bool isE2 = (lane >= 62);
    const float* Ib = I + (size_t)b * (IMG * IMG);
    const float* Jb = J + (size_t)b * (IMG * IMG);

    // bf16-packed ring: 9 rows x 5 quantities x 4 cols = 90 VGPRs
    __hip_bfloat162 gI[9][2], gJ[9][2], gII[9][2], gJJ[9][2], gIJ[9][2];
    const __hip_bfloat162 z2 = __float22bfloat162_rn(make_float2(0.f, 0.f));
#pragma unroll
    for (int k = 0; k < 9; ++k) {
      gI[k][0] = z2; gI[k][1] = z2; gJ[k][0] = z2; gJ[k][1] = z2;
      gII[k][0] = z2; gII[k][1] = z2; gJJ[k][0] = z2; gJJ[k][1] = z2;
      gIJ[k][0] = z2; gIJ[k][1] = z2;
    }
    float wI[4] = {0,0,0,0}, wJ[4] = {0,0,0,0}, wII[4] = {0,0,0,0},
          wJJ[4] = {0,0,0,0}, wIJ[4] = {0,0,0,0};
    float prevI[4] = {0,0,0,0};
    float4 PI = make_float4(0.f, 0.f, 0.f, 0.f);
    float4 PJ = make_float4(0.f, 0.f, 0.f, 0.f);

    for (int tc = 0; tc < NTC; ++tc) {
#pragma unroll
      for (int u = 0; u < 9; ++u) {
        const int t = tc * 9 + u;
        if (t < NSTEP) {
          const int r = R0 - 1 + t;      // input row
          float iw[12], jw[12];
          if (r >= 0 && r < IMG) {       // wave-uniform
            const float* rpI = Ib + ((size_t)r << 10);
            const float* rpJ = Jb + ((size_t)r << 10);
            // Loads per image: 1 full-wave float4 + 1 masked float4 (3 lanes).
            float4 A1 = *(const float4*)(rpI + c0);
            float4 B1 = *(const float4*)(rpJ + c0);
            if (do_patch) {              // divergent, 3 lanes
              PI = *(const float4*)(rpI + cp);
              PJ = *(const float4*)(rpJ + cp);
            }
            // left halo (col c0-1) from lane-1's A1.w; lane 0 from patch
            float lhI = __shfl_up(A1.w, 1), lhJ = __shfl_up(B1.w, 1);
            // lane 63's right halo cols base+256..259 from lane 62's patch
            float s5I = __shfl_up(PI.x, 1), s6I = __shfl_up(PI.y, 1);
            float s7I = __shfl_up(PI.z, 1), s8I = __shfl_up(PI.w, 1);
            float s5J = __shfl_up(PJ.x, 1), s6J = __shfl_up(PJ.y, 1);
            float s7J = __shfl_up(PJ.z, 1), s8J = __shfl_up(PJ.w, 1);
            // right halo from neighbor lanes
            float d5I = __shfl_down(A1.x, 1), d6I = __shfl_down(A1.y, 1);
            float d7I = __shfl_down(A1.z, 1), d8I = __shfl_down(A1.w, 1);
            float d9I = __shfl_down(A1.x, 2), d10I = __shfl_down(A1.y, 2);
            float d11I = __shfl_down(A1.z, 2);
            float d5J = __shfl_down(B1.x, 1), d6J = __shfl_down(B1.y, 1);
            float d7J = __shfl_down(B1.z, 1), d8J = __shfl_down(B1.w, 1);
            float d9J = __shfl_down(B1.x, 2), d10J = __shfl_down(B1.y, 2);
            float d11J = __shfl_down(B1.z, 2);
            iw[0] = isL ? PI.w : lhI;         jw[0] = isL ? PJ.w : lhJ;
            iw[1] = A1.x; iw[2] = A1.y; iw[3] = A1.z; iw[4] = A1.w;
            jw[1] = B1.x; jw[2] = B1.y; jw[3] = B1.z; jw[4] = B1.w;
            iw[5] = isE1 ? s5I : d5I;  jw[5] = isE1 ? s5J : d5J;
            iw[6] = isE1 ? s6I : d6I;  jw[6] = isE1 ? s6J : d6J;
            iw[7] = isE1 ? s7I : d7I;  jw[7] = isE1 ? s7J : d7J;
            iw[8] = isE1 ? s8I : d8I;  jw[8] = isE1 ? s8J : d8J;
            iw[9]  = isE2 ? PI.x : d9I;   jw[9]  = isE2 ? PJ.x : d9J;
            iw[10] = isE2 ? PI.y : d10I;  jw[10] = isE2 ? PJ.y : d10J;
            iw[11] = isE2 ? PI.z : d11I;  jw[11] = isE2 ? PJ.z : d11J;
          } else {
#pragma unroll
            for (int p = 0; p < 12; ++p) { iw[p] = 0.f; jw[p] = 0.f; }
          }

          hsum_update(iw, wI, gI[u]);
          hsum_update(jw, wJ, gJ[u]);
          hsum_update_sq(iw, iw, wII, gII[u]);
          hsum_update_sq(jw, jw, wJJ, gJJ[u]);
          hsum_update_sq(iw, jw, wIJ, gIJ[u]);

          // smoothness dy: pairs (r-1, r) with r-1 owned by this strip
          if (r >= R0 + 1 && r <= R0 + RS && r <= IMG - 1) {   // uniform
#pragma unroll
            for (int q = 0; q < 4; ++q) {
              float d = iw[1 + q] - prevI[q];
              acc_sm = fmaf(d, d, acc_sm);
            }
          }
          // smoothness dx at owned rows
          if (r >= R0 && r <= R0 + RS - 1 && r <= IMG - 1) {   // uniform
#pragma unroll
            for (int q = 0; q < 4; ++q) {
              float d = iw[2 + q] - iw[1 + q];
              d = (c0 + q < IMG - 1) ? d : 0.f;
              acc_sm = fmaf(d, d, acc_sm);
            }
          }
          prevI[0] = iw[1]; prevI[1] = iw[2]; prevI[2] = iw[3]; prevI[3] = iw[4];

          // emit output row oy = R0 + t - 8 once window complete
          if (t >= 8) {                                        // uniform
            const int oy = R0 + t - 8;
            if (oy < OUTW) {                                   // uniform
#pragma unroll
              for (int q = 0; q < 4; ++q) {
                if (c0 + q < OUTW) {
                  float cross = fmaf(-(wI[q] * wJ[q]), INV81, wIJ[q]);
                  float iva   = fmaf(-(wI[q] * wI[q]), INV81, wII[q]);
                  float jva   = fmaf(-(wJ[q] * wJ[q]), INV81, wJJ[q]);
                  float den   = fmaf(iva, jva, EPSF);
                  acc_cc += cross * cross * __builtin_amdgcn_rcpf(den);
                }
              }
            }
          }
        }
      }
    }
  }

  // per-wave shuffle reduce, then per-block LDS reduce; one double2 per block
  float vc = acc_cc, vs = acc_sm;
#pragma unroll
  for (int off = 32; off > 0; off >>= 1) {
    vc += __shfl_down(vc, off);
    vs += __shfl_down(vs, off);
  }
  __shared__ double2 red[4];
  if (lane == 0) red[threadIdx.x >> 6] = make_double2((double)vc, (double)vs);
  __syncthreads();
  if (threadIdx.x == 0) {
    partial[blockIdx.x] = make_double2(red[0].x + red[1].x + red[2].x + red[3].x,
                                       red[0].y + red[1].y + red[2].y + red[3].y);
  }
}

__global__ __launch_bounds__(256) void fin_kernel(const double2* __restrict__ partial,
                                                  float* __restrict__ out) {
  double s_cc = 0.0, s_sm = 0.0;
  for (int i = threadIdx.x; i < NBLK; i += 256) {
    double2 p = partial[i];
    s_cc += p.x; s_sm += p.y;
  }
#pragma unroll
  for (int off = 32; off > 0; off >>= 1) {
    s_cc += __shfl_down(s_cc, off);
    s_sm += __shfl_down(s_sm, off);
  }
  __shared__ double r1[4], r2[4];
  if ((threadIdx.x & 63) == 0) { r1[threadIdx.x >> 6] = s_cc; r2[threadIdx.x >> 6] = s_sm; }
  __syncthreads();
  if (threadIdx.x == 0) {
    const double cc = (r1[0] + r1[1] + r1[2] + r1[3]) /
                      (double)((size_t)NBATCH * OUTW * OUTW);
    const double sm = (r2[0] + r2[1] + r2[2] + r2[3]) /
                      (2.0 * (double)((size_t)NBATCH * IMG * (IMG - 1)));
    out[0] = (float)(-cc + 0.1 * sm);
  }
}

extern "C" void kernel_launch(void* const* d_in, const int* in_sizes, int n_in,
                              void* d_out, int out_size, void* d_ws, size_t ws_size,
                              hipStream_t stream) {
  const float* y  = (const float*)d_in[0];
  const float* yt = (const float*)d_in[1];
  float* out = (float*)d_out;
  double2* partial = (double2*)d_ws;
  fused_kernel<<<NBLK, 256, 0, stream>>>(y, yt, partial);
  fin_kernel<<<1, 256, 0, stream>>>(partial, out);
}